// Round 2
// baseline (182.441 us; speedup 1.0000x reference)
//
#include <hip/hip_runtime.h>
#include <hip/hip_bf16.h>

typedef unsigned short u16;
typedef __attribute__((ext_vector_type(8))) short short8;
typedef __attribute__((ext_vector_type(4))) short short4_;
typedef __attribute__((ext_vector_type(4))) float f32x4;
typedef __attribute__((ext_vector_type(4))) unsigned int uint4_;

#define B_ 4
#define T_ 2048
#define D_ 512
#define H_ 8
#define M_ (B_*T_)          // 8192 rows
#define INV2PI 0.15915494309189535f

// ---- static device workspace (avoids d_ws size uncertainty) ----
__device__ u16   g_zb[M_*D_];           // z in bf16           8 MB
__device__ u16   g_wqk[2*D_*D_];        // W_qk bf16           1 MB
__device__ u16   g_wout[D_*D_];         // W_out bf16        0.5 MB
__device__ float g_qk[(size_t)M_*2*D_]; // z @ Wqk^T fp32     32 MB
__device__ u16   g_qb[M_*D_];           // normalized q /2pi   8 MB
__device__ u16   g_kb[M_*D_];           // normalized k        8 MB
__device__ u16   g_kT[(size_t)B_*H_*64*T_]; // k transposed    8 MB
__device__ u16   g_force[M_*D_];        // attention output    8 MB

__device__ inline u16 f2bf(float f) {
  union { __hip_bfloat16 h; u16 u; } cv;
  cv.h = __float2bfloat16(f);
  return cv.u;
}

__device__ inline float sin2pi(float x) {
#if __has_builtin(__builtin_amdgcn_sinf)
  return __builtin_amdgcn_sinf(x);   // v_sin_f32: sin(2*pi*x)
#else
  return __sinf(x * 6.283185307179586f);
#endif
}

// ---- fp32 -> bf16 conversion into static buffers ----
template<int WHICH>
__global__ void cvt_kernel(const float* __restrict__ in) {
  constexpr int n4 = (WHICH == 0) ? (M_*D_/4) : (WHICH == 1) ? (2*D_*D_/4) : (D_*D_/4);
  u16* out = (WHICH == 0) ? g_zb : (WHICH == 1) ? g_wqk : g_wout;
  int i = blockIdx.x*256 + threadIdx.x;
  if (i < n4) {
    f32x4 v = *(const f32x4*)(in + (size_t)i*4);
    short4_ o;
    o[0] = (short)f2bf(v[0]); o[1] = (short)f2bf(v[1]);
    o[2] = (short)f2bf(v[2]); o[3] = (short)f2bf(v[3]);
    *(short4_*)(out + (size_t)i*4) = o;
  }
}

// ---- GEMM C[m,n] = sum_k A[m,k]*Bt[n,k]  (K=512 fixed) ----
// MODE 0: g_zb @ g_wqk^T -> g_qk (N=1024)
// MODE 1: g_force @ g_wout^T -> Cout (N=512), + omega[n] + b_out[n]
template<int MODE>
__global__ __launch_bounds__(256, 2)
void gemm_bt(float* __restrict__ Cout, const float* __restrict__ add1,
             const float* __restrict__ add2) {
  constexpr int K = 512;
  constexpr int N = (MODE == 0) ? 1024 : 512;
  const u16* A  = (MODE == 0) ? g_zb  : g_force;
  const u16* Bt = (MODE == 0) ? g_wqk : g_wout;
  float* C = (MODE == 0) ? g_qk : Cout;

  __shared__ u16 As[128*72];
  __shared__ u16 Bs[128*72];
  const int m0 = blockIdx.x*128, n0 = blockIdx.y*128;
  const int t = threadIdx.x;
  const int w = t>>6, l = t&63;
  const int wr = (w>>1)*64, wc = (w&1)*64;
  const int lg = l>>4, li = l&15;
  const int srow = t>>3, scol = (t&7)*8;

  f32x4 acc[4][4] = {};

  for (int k0 = 0; k0 < K; k0 += 64) {
#pragma unroll
    for (int p = 0; p < 4; ++p) {
      int r = srow + p*32;
      *(short8*)&As[r*72 + scol] = *(const short8*)&A [(size_t)(m0+r)*K + k0 + scol];
      *(short8*)&Bs[r*72 + scol] = *(const short8*)&Bt[(size_t)(n0+r)*K + k0 + scol];
    }
    __syncthreads();
#pragma unroll
    for (int ks = 0; ks < 2; ++ks) {
      short8 af[4], bf[4];
#pragma unroll
      for (int i = 0; i < 4; ++i)
        af[i] = *(const short8*)&As[(wr + i*16 + li)*72 + ks*32 + lg*8];
#pragma unroll
      for (int j = 0; j < 4; ++j)
        bf[j] = *(const short8*)&Bs[(wc + j*16 + li)*72 + ks*32 + lg*8];
#pragma unroll
      for (int i = 0; i < 4; ++i)
#pragma unroll
        for (int j = 0; j < 4; ++j)
          acc[i][j] = __builtin_amdgcn_mfma_f32_16x16x32_bf16(af[i], bf[j], acc[i][j], 0, 0, 0);
    }
    __syncthreads();
  }

#pragma unroll
  for (int i = 0; i < 4; ++i) {
#pragma unroll
    for (int j = 0; j < 4; ++j) {
      int col = n0 + wc + j*16 + li;
      float badd = 0.f;
      if (MODE == 1) badd = add1[col] + add2[col];
#pragma unroll
      for (int r = 0; r < 4; ++r) {
        int row = m0 + wr + i*16 + lg*4 + r;
        C[(size_t)row*N + col] = acc[i][j][r] + badd;
      }
    }
  }
}

// ---- per-head l2 normalize; q additionally scaled by 1/(2*pi) ----
__global__ void normalize_qk_kernel() {
  int gid = blockIdx.x*256 + threadIdx.x;
  int l = gid & 63;
  int wv = gid >> 6;            // one wave per 64-element chunk
  int row = wv >> 4, c = wv & 15;
  float x = g_qk[(size_t)row*1024 + c*64 + l];
  float s = x*x;
#pragma unroll
  for (int off = 32; off; off >>= 1) s += __shfl_xor(s, off);
  float scale = 1.0f / fmaxf(sqrtf(s), 1e-12f);
  if (c < 8) g_qb[(size_t)row*512 + c*64 + l]     = f2bf(x*scale*INV2PI);
  else       g_kb[(size_t)row*512 + (c-8)*64 + l] = f2bf(x*scale);
}

// ---- transpose k to [bh][d][t] layout ----
__global__ void transpose_k_kernel() {
  __shared__ u16 tile[64*72];
  const int t0 = blockIdx.x*64, bh = blockIdx.y;
  const int b = bh>>3, h = bh&7;
  const int t = threadIdx.x;
  {
    int r = t>>2, cs = (t&3)*16;
    const u16* src = g_kb + (size_t)(b*T_ + t0 + r)*D_ + h*64 + cs;
    *(short8*)&tile[r*72 + cs]     = *(const short8*)(src);
    *(short8*)&tile[r*72 + cs + 8] = *(const short8*)(src + 8);
  }
  __syncthreads();
  {
    int d = t>>2, ts = (t&3)*16;
    short8 o0, o1;
#pragma unroll
    for (int j = 0; j < 8; ++j) {
      o0[j] = (short)tile[(ts + j)*72 + d];
      o1[j] = (short)tile[(ts + 8 + j)*72 + d];
    }
    u16* dst = g_kT + ((size_t)bh*64 + d)*T_ + t0 + ts;
    *(short8*)(dst)     = o0;
    *(short8*)(dst + 8) = o1;
  }
}

// ---- fused  force = sin(Q K^T) K  per (b,h) ----
// Swapped-operand trick: compute S' = K*Q^T so the C-layout (col = q-row)
// matches the A-operand row mapping for the PV MFMA; sin + bf16 pack stays
// entirely in registers. The induced k-slot permutation pi(8hg+e) =
// 4hg+e (e<4) / 16+4hg+e-4 (e>=4) is matched on the B side by reading K^T
// as two 4-element runs per fragment -> MFMA sums over a bijection of k.
__global__ __launch_bounds__(256, 2)
void kuramoto_attn_kernel() {
  __shared__ u16 Qs[128*72];
  __shared__ u16 Ks[128*72];
  __shared__ u16 KTs[64*136];
  const int qt = blockIdx.x;      // q tile (16)
  const int bh = blockIdx.y;      // (32)
  const int b = bh>>3, h = bh&7;
  const int t = threadIdx.x;
  const int w = t>>6, l = t&63;
  const int lg = l>>4, li = l&15;

  {
    int r = t>>3, cs = (t&7)*8;
#pragma unroll
    for (int p = 0; p < 4; ++p) {
      int rr = r + p*32;
      *(short8*)&Qs[rr*72 + cs] =
        *(const short8*)&g_qb[(size_t)(b*T_ + qt*128 + rr)*D_ + h*64 + cs];
    }
  }

  f32x4 acc_o[2][4] = {};

  for (int kt = 0; kt < 16; ++kt) {
    __syncthreads();
    {
      int r = t>>3, cs = (t&7)*8;
#pragma unroll
      for (int p = 0; p < 4; ++p) {
        int rr = r + p*32;
        *(short8*)&Ks[rr*72 + cs] =
          *(const short8*)&g_kb[(size_t)(b*T_ + kt*128 + rr)*D_ + h*64 + cs];
      }
      int d = t>>4, ks2 = (t&15)*8;
#pragma unroll
      for (int p = 0; p < 4; ++p) {
        int dd = d + p*16;
        *(short8*)&KTs[dd*136 + ks2] =
          *(const short8*)&g_kT[((size_t)bh*64 + dd)*T_ + kt*128 + ks2];
      }
    }
    __syncthreads();

    // S'[kk 0..127][m w*32..w*32+31] = K . Q^T   (pre-scaled by 1/2pi via q)
    f32x4 sacc[8][2] = {};
#pragma unroll
    for (int ks = 0; ks < 2; ++ks) {
      short8 af[8], bq[2];
#pragma unroll
      for (int i = 0; i < 8; ++i)
        af[i] = *(const short8*)&Ks[(i*16 + li)*72 + ks*32 + lg*8];
#pragma unroll
      for (int j = 0; j < 2; ++j)
        bq[j] = *(const short8*)&Qs[(w*32 + j*16 + li)*72 + ks*32 + lg*8];
#pragma unroll
      for (int i = 0; i < 8; ++i)
#pragma unroll
        for (int j = 0; j < 2; ++j)
          sacc[i][j] = __builtin_amdgcn_mfma_f32_16x16x32_bf16(af[i], bq[j], sacc[i][j], 0, 0, 0);
    }

    // sin -> bf16, packed in pairs (r0|r1, r2|r3) per fragment
    unsigned int pb2[8][2][2];
#pragma unroll
    for (int i = 0; i < 8; ++i)
#pragma unroll
      for (int j = 0; j < 2; ++j) {
        pb2[i][j][0] = (unsigned int)f2bf(sin2pi(sacc[i][j][0]))
                     | ((unsigned int)f2bf(sin2pi(sacc[i][j][1])) << 16);
        pb2[i][j][1] = (unsigned int)f2bf(sin2pi(sacc[i][j][2]))
                     | ((unsigned int)f2bf(sin2pi(sacc[i][j][3])) << 16);
      }

    // O[m][d] += P'. K  ; a-frag slots from registers, b-frag from KTs
#pragma unroll
    for (int kks = 0; kks < 4; ++kks) {
      short8 apv[2];
#pragma unroll
      for (int j = 0; j < 2; ++j) {
        union { uint4_ u; short8 s; } cvt;
        cvt.u[0] = pb2[2*kks  ][j][0];
        cvt.u[1] = pb2[2*kks  ][j][1];
        cvt.u[2] = pb2[2*kks+1][j][0];
        cvt.u[3] = pb2[2*kks+1][j][1];
        apv[j] = cvt.s;
      }
#pragma unroll
      for (int di = 0; di < 4; ++di) {
        short4_ b1 = *(const short4_*)&KTs[(di*16 + li)*136 + kks*32 + lg*4];
        short4_ b2 = *(const short4_*)&KTs[(di*16 + li)*136 + kks*32 + 16 + lg*4];
        union { short4_ h[2]; short8 v; } bu;
        bu.h[0] = b1; bu.h[1] = b2;
#pragma unroll
        for (int j = 0; j < 2; ++j)
          acc_o[j][di] = __builtin_amdgcn_mfma_f32_16x16x32_bf16(apv[j], bu.v, acc_o[j][di], 0, 0, 0);
      }
    }
  }

  // write force as bf16 (row-major [b*T+t][h*64+d])
#pragma unroll
  for (int j = 0; j < 2; ++j)
#pragma unroll
    for (int di = 0; di < 4; ++di)
#pragma unroll
      for (int r = 0; r < 4; ++r) {
        int row = b*T_ + qt*128 + w*32 + j*16 + lg*4 + r;
        int col = h*64 + di*16 + li;
        g_force[(size_t)row*D_ + col] = f2bf(acc_o[j][di][r]);
      }
}

extern "C" void kernel_launch(void* const* d_in, const int* in_sizes, int n_in,
                              void* d_out, int out_size, void* d_ws, size_t ws_size,
                              hipStream_t stream) {
  // inputs: t(unused), z, omega, W_qk, W_out, b_out  (all fp32)
  const float* z     = (const float*)d_in[1];
  const float* omega = (const float*)d_in[2];
  const float* Wqk   = (const float*)d_in[3];
  const float* Wout  = (const float*)d_in[4];
  const float* bout  = (const float*)d_in[5];
  float* out = (float*)d_out;

  cvt_kernel<0><<<M_*D_/4/256, 256, 0, stream>>>(z);      // 4096 blocks
  cvt_kernel<1><<<2*D_*D_/4/256, 256, 0, stream>>>(Wqk);  // 512
  cvt_kernel<2><<<D_*D_/4/256, 256, 0, stream>>>(Wout);   // 256

  gemm_bt<0><<<dim3(M_/128, 1024/128), 256, 0, stream>>>(nullptr, nullptr, nullptr);

  normalize_qk_kernel<<<M_*16*64/256, 256, 0, stream>>>(); // 32768 blocks

  transpose_k_kernel<<<dim3(T_/64, B_*H_), 256, 0, stream>>>();

  kuramoto_attn_kernel<<<dim3(T_/128, B_*H_), 256, 0, stream>>>();

  gemm_bt<1><<<dim3(M_/128, 512/128), 256, 0, stream>>>(out, omega, bout);
}

// Round 3
// 168.768 us; speedup vs baseline: 1.0810x; 1.0810x over previous
//
#include <hip/hip_runtime.h>
#include <hip/hip_bf16.h>

typedef unsigned short u16;
typedef __attribute__((ext_vector_type(8))) short short8;
typedef __attribute__((ext_vector_type(4))) short short4_;
typedef __attribute__((ext_vector_type(4))) float f32x4;

#define B_ 4
#define T_ 2048
#define D_ 512
#define H_ 8
#define M_ (B_*T_)          // 8192 rows
#define INV2PI 0.15915494309189535f

// ---- static device workspace ----
__device__ u16   g_qb[M_*D_];               // normalized q /2pi   8 MB
__device__ u16   g_kb[M_*D_];               // normalized k        8 MB
__device__ u16   g_kTp[(size_t)B_*H_*64*T_];// k^T, slot-permuted  8 MB
__device__ float g_fA[(size_t)M_*D_];       // force half kh=0    17 MB
__device__ float g_fB[(size_t)M_*D_];       // force half kh=1    17 MB

__device__ inline u16 f2bf(float f) {
  union { __hip_bfloat16 h; u16 u; } cv;
  cv.h = __float2bfloat16(f);
  return cv.u;
}

__device__ inline float sin2pi(float x) {
#if __has_builtin(__builtin_amdgcn_sinf)
  return __builtin_amdgcn_sinf(x);   // v_sin_f32: sin(2*pi*x)
#else
  return __sinf(x * 6.283185307179586f);
#endif
}

__device__ inline short8 cvt8(f32x4 a, f32x4 b) {
  short8 o;
  o[0]=(short)f2bf(a[0]); o[1]=(short)f2bf(a[1]); o[2]=(short)f2bf(a[2]); o[3]=(short)f2bf(a[3]);
  o[4]=(short)f2bf(b[0]); o[5]=(short)f2bf(b[1]); o[6]=(short)f2bf(b[2]); o[7]=(short)f2bf(b[3]);
  return o;
}

// slot permutation for the PV A-operand register layout:
// position p (0..31) in permuted storage holds original k = perm5(p)
__device__ inline int perm5(int p) {
  int lg = p >> 3, e = p & 7;
  return (e < 4) ? lg*4 + e : 16 + lg*4 + (e & 3);
}

// ---- GEMM C[m,n] = sum_k A[m,k]*Bt[n,k]  (K=512), fp32 in, cvt in staging ----
// MODE 0: z @ Wqk^T, epilogue = per-64-chunk l2-normalize -> g_qb (x 1/2pi) / g_kb
// MODE 1: (g_fA+g_fB) @ Wout^T + omega + b_out -> Cout fp32
template<int MODE>
__global__ __launch_bounds__(256, 2)
void gemm_bt(float* __restrict__ Cout, const float* __restrict__ add1,
             const float* __restrict__ add2, const float* __restrict__ Afp,
             const float* __restrict__ Bfp) {
  constexpr int K = 512;
  constexpr int N = (MODE == 0) ? 1024 : 512;
  __shared__ u16 As[128*72];
  __shared__ u16 Bs[128*72];
  const int m0 = blockIdx.x*128, n0 = blockIdx.y*128;
  const int t = threadIdx.x;
  const int w = t>>6, l = t&63;
  const int wr = (w>>1)*64, wc = (w&1)*64;
  const int lg = l>>4, li = l&15;
  const int srow = t>>3, scol = (t&7)*8;

  f32x4 acc[4][4] = {};

  for (int k0 = 0; k0 < K; k0 += 64) {
#pragma unroll
    for (int p = 0; p < 4; ++p) {
      int r = srow + p*32;
      {
        f32x4 b0 = *(const f32x4*)&Bfp[(size_t)(n0+r)*K + k0 + scol];
        f32x4 b1 = *(const f32x4*)&Bfp[(size_t)(n0+r)*K + k0 + scol + 4];
        *(short8*)&Bs[r*72 + scol] = cvt8(b0, b1);
      }
      if (MODE == 0) {
        f32x4 a0 = *(const f32x4*)&Afp[(size_t)(m0+r)*K + k0 + scol];
        f32x4 a1 = *(const f32x4*)&Afp[(size_t)(m0+r)*K + k0 + scol + 4];
        *(short8*)&As[r*72 + scol] = cvt8(a0, a1);
      } else {
        size_t off = (size_t)(m0+r)*K + k0 + scol;
        f32x4 a0 = *(const f32x4*)&g_fA[off];
        f32x4 a1 = *(const f32x4*)&g_fA[off+4];
        f32x4 c0 = *(const f32x4*)&g_fB[off];
        f32x4 c1 = *(const f32x4*)&g_fB[off+4];
        a0 += c0; a1 += c1;
        *(short8*)&As[r*72 + scol] = cvt8(a0, a1);
      }
    }
    __syncthreads();
#pragma unroll
    for (int ks = 0; ks < 2; ++ks) {
      short8 af[4], bf[4];
#pragma unroll
      for (int i = 0; i < 4; ++i)
        af[i] = *(const short8*)&As[(wr + i*16 + li)*72 + ks*32 + lg*8];
#pragma unroll
      for (int j = 0; j < 4; ++j)
        bf[j] = *(const short8*)&Bs[(wc + j*16 + li)*72 + ks*32 + lg*8];
#pragma unroll
      for (int i = 0; i < 4; ++i)
#pragma unroll
        for (int j = 0; j < 4; ++j)
          acc[i][j] = __builtin_amdgcn_mfma_f32_16x16x32_bf16(af[i], bf[j], acc[i][j], 0, 0, 0);
    }
    __syncthreads();
  }

  if (MODE == 0) {
    // fused per-head l2 normalize: each wave's 64-col tile is exactly one chunk
    const bool isq = (n0 < 512);
    u16* dst = isq ? g_qb : g_kb;
    const float qs = isq ? INV2PI : 1.0f;
    const int nb = (isq ? n0 : n0 - 512) + wc;
#pragma unroll
    for (int i = 0; i < 4; ++i) {
#pragma unroll
      for (int r = 0; r < 4; ++r) {
        float s = 0.f;
#pragma unroll
        for (int j = 0; j < 4; ++j) s += acc[i][j][r]*acc[i][j][r];
#pragma unroll
        for (int off = 1; off < 16; off <<= 1) s += __shfl_xor(s, off);
        float sc = qs / fmaxf(sqrtf(s), 1e-12f);
        int row = m0 + wr + i*16 + lg*4 + r;
#pragma unroll
        for (int j = 0; j < 4; ++j)
          dst[(size_t)row*D_ + nb + j*16 + li] = f2bf(acc[i][j][r]*sc);
      }
    }
  } else {
#pragma unroll
    for (int i = 0; i < 4; ++i) {
#pragma unroll
      for (int j = 0; j < 4; ++j) {
        int col = n0 + wc + j*16 + li;
        float badd = add1[col] + add2[col];
#pragma unroll
        for (int r = 0; r < 4; ++r) {
          int row = m0 + wr + i*16 + lg*4 + r;
          Cout[(size_t)row*N + col] = acc[i][j][r] + badd;
        }
      }
    }
  }
}

// ---- transpose k to [bh][d][t'] with PV slot permutation baked in ----
__global__ void transpose_k_kernel() {
  __shared__ u16 tile[64*72];
  const int t0 = blockIdx.x*64, bh = blockIdx.y;
  const int b = bh>>3, h = bh&7;
  const int t = threadIdx.x;
  {
    int r = t>>2, cs = (t&3)*16;
    const u16* src = g_kb + (size_t)(b*T_ + t0 + r)*D_ + h*64 + cs;
    *(short8*)&tile[r*72 + cs]     = *(const short8*)(src);
    *(short8*)&tile[r*72 + cs + 8] = *(const short8*)(src + 8);
  }
  __syncthreads();
  {
    int d = t>>2, ts = (t&3)*16;
    short8 o0, o1;
#pragma unroll
    for (int j = 0; j < 8; ++j) {
      int p0 = ts + j, p1 = ts + 8 + j;
      int s0 = (p0 & ~31) | perm5(p0 & 31);
      int s1 = (p1 & ~31) | perm5(p1 & 31);
      o0[j] = (short)tile[s0*72 + d];
      o1[j] = (short)tile[s1*72 + d];
    }
    u16* dst = g_kTp + ((size_t)bh*64 + d)*T_ + t0 + ts;
    *(short8*)(dst)     = o0;
    *(short8*)(dst + 8) = o1;
  }
}

// ---- fused  force = sin(Q K^T) K  per (b,h), kt-split x2 ----
// Swapped QK^T keeps sin+pack in registers; permuted g_kTp makes the PV
// B-frag a single balanced ds_read_b128. Q frags live in registers.
__global__ __launch_bounds__(256, 4)
void kuramoto_attn_kernel() {
  __shared__ u16 Ks[128*72];
  __shared__ u16 KTs[64*136];
  const int wg  = blockIdx.x;
  const int wgp = (wg & 7)*128 + (wg >> 3);   // XCD swizzle: 4 bh per XCD
  const int bh = wgp >> 5, qt = (wgp & 31) >> 1, kh = wgp & 1;
  const int b = bh >> 3, h = bh & 7;
  const int t = threadIdx.x;
  const int w = t>>6, l = t&63;
  const int lg = l>>4, li = l&15;

  // loop-invariant Q fragments (16 VGPR)
  short8 bq[2][2];
#pragma unroll
  for (int ks = 0; ks < 2; ++ks)
#pragma unroll
    for (int j = 0; j < 2; ++j)
      bq[ks][j] = *(const short8*)&g_qb[(size_t)(b*T_ + qt*128 + w*32 + j*16 + li)*D_
                                        + h*64 + ks*32 + lg*8];

  f32x4 acc_o[2][4] = {};

  for (int kt = kh*8; kt < kh*8 + 8; ++kt) {
    __syncthreads();
    {
      int r = t>>3, cs = (t&7)*8;
#pragma unroll
      for (int p = 0; p < 4; ++p) {
        int rr = r + p*32;
        *(short8*)&Ks[rr*72 + cs] =
          *(const short8*)&g_kb[(size_t)(b*T_ + kt*128 + rr)*D_ + h*64 + cs];
      }
      int d = t>>4, ks2 = (t&15)*8;
#pragma unroll
      for (int p = 0; p < 4; ++p) {
        int dd = d + p*16;
        *(short8*)&KTs[dd*136 + ks2] =
          *(const short8*)&g_kTp[((size_t)bh*64 + dd)*T_ + kt*128 + ks2];
      }
    }
    __syncthreads();

#pragma unroll
    for (int kkp = 0; kkp < 4; ++kkp) {
      f32x4 sacc[2][2] = {};
#pragma unroll
      for (int ks = 0; ks < 2; ++ks) {
        short8 af0 = *(const short8*)&Ks[((2*kkp  )*16 + li)*72 + ks*32 + lg*8];
        short8 af1 = *(const short8*)&Ks[((2*kkp+1)*16 + li)*72 + ks*32 + lg*8];
#pragma unroll
        for (int j = 0; j < 2; ++j) {
          sacc[0][j] = __builtin_amdgcn_mfma_f32_16x16x32_bf16(af0, bq[ks][j], sacc[0][j], 0,0,0);
          sacc[1][j] = __builtin_amdgcn_mfma_f32_16x16x32_bf16(af1, bq[ks][j], sacc[1][j], 0,0,0);
        }
      }
      // sin -> bf16 pack: apv slot s holds P[q][perm5-permuted k], matched by g_kTp
      short8 apv[2];
#pragma unroll
      for (int j = 0; j < 2; ++j) {
        union { unsigned int u[4]; short8 s; } cv;
        cv.u[0] = (unsigned)f2bf(sin2pi(sacc[0][j][0])) | ((unsigned)f2bf(sin2pi(sacc[0][j][1]))<<16);
        cv.u[1] = (unsigned)f2bf(sin2pi(sacc[0][j][2])) | ((unsigned)f2bf(sin2pi(sacc[0][j][3]))<<16);
        cv.u[2] = (unsigned)f2bf(sin2pi(sacc[1][j][0])) | ((unsigned)f2bf(sin2pi(sacc[1][j][1]))<<16);
        cv.u[3] = (unsigned)f2bf(sin2pi(sacc[1][j][2])) | ((unsigned)f2bf(sin2pi(sacc[1][j][3]))<<16);
        apv[j] = cv.s;
      }
#pragma unroll
      for (int di = 0; di < 4; ++di) {
        short8 bv = *(const short8*)&KTs[(di*16 + li)*136 + kkp*32 + lg*8];
#pragma unroll
        for (int j = 0; j < 2; ++j)
          acc_o[j][di] = __builtin_amdgcn_mfma_f32_16x16x32_bf16(apv[j], bv, acc_o[j][di], 0,0,0);
      }
    }
  }

  float* F = kh ? g_fB : g_fA;
#pragma unroll
  for (int j = 0; j < 2; ++j)
#pragma unroll
    for (int di = 0; di < 4; ++di)
#pragma unroll
      for (int r = 0; r < 4; ++r) {
        int row = b*T_ + qt*128 + w*32 + j*16 + lg*4 + r;
        int col = h*64 + di*16 + li;
        F[(size_t)row*D_ + col] = acc_o[j][di][r];
      }
}

extern "C" void kernel_launch(void* const* d_in, const int* in_sizes, int n_in,
                              void* d_out, int out_size, void* d_ws, size_t ws_size,
                              hipStream_t stream) {
  // inputs: t(unused), z, omega, W_qk, W_out, b_out  (all fp32)
  const float* z     = (const float*)d_in[1];
  const float* omega = (const float*)d_in[2];
  const float* Wqk   = (const float*)d_in[3];
  const float* Wout  = (const float*)d_in[4];
  const float* bout  = (const float*)d_in[5];
  float* out = (float*)d_out;

  gemm_bt<0><<<dim3(M_/128, 1024/128), 256, 0, stream>>>(nullptr, nullptr, nullptr, z, Wqk);
  transpose_k_kernel<<<dim3(T_/64, B_*H_), 256, 0, stream>>>();
  kuramoto_attn_kernel<<<1024, 256, 0, stream>>>();
  gemm_bt<1><<<dim3(M_/128, 512/128), 256, 0, stream>>>(out, omega, bout, nullptr, Wout);
}

// Round 5
// 160.069 us; speedup vs baseline: 1.1398x; 1.0543x over previous
//
#include <hip/hip_runtime.h>
#include <hip/hip_bf16.h>

typedef unsigned short u16;
typedef __attribute__((ext_vector_type(8))) short short8;
typedef __attribute__((ext_vector_type(4))) short short4_;
typedef __attribute__((ext_vector_type(4))) float f32x4;

#define B_ 4
#define T_ 2048
#define D_ 512
#define H_ 8
#define M_ (B_*T_)          // 8192 rows
#define INV2PI 0.15915494309189535f

// ---- static device workspace ----
__device__ u16   g_qb[M_*D_];               // normalized q /2pi   8 MB
__device__ u16   g_kb[M_*D_];               // normalized k        8 MB
__device__ u16   g_kTp[(size_t)B_*H_*64*T_];// k^T, slot-permuted  8 MB
__device__ float g_fA[(size_t)M_*D_];       // force half kh=0    17 MB
__device__ float g_fB[(size_t)M_*D_];       // force half kh=1    17 MB

__device__ inline u16 f2bf(float f) {
  union { __hip_bfloat16 h; u16 u; } cv;
  cv.h = __float2bfloat16(f);
  return cv.u;
}

__device__ inline float sin2pi(float x) {
#if __has_builtin(__builtin_amdgcn_sinf)
  return __builtin_amdgcn_sinf(x);   // v_sin_f32: sin(2*pi*x)
#else
  return __sinf(x * 6.283185307179586f);
#endif
}

__device__ inline short8 cvt8(f32x4 a, f32x4 b) {
  short8 o;
  o[0]=(short)f2bf(a[0]); o[1]=(short)f2bf(a[1]); o[2]=(short)f2bf(a[2]); o[3]=(short)f2bf(a[3]);
  o[4]=(short)f2bf(b[0]); o[5]=(short)f2bf(b[1]); o[6]=(short)f2bf(b[2]); o[7]=(short)f2bf(b[3]);
  return o;
}

// slot permutation for the PV A-operand register layout:
// position p (0..31) in permuted storage holds original k = perm5(p)
__device__ inline int perm5(int p) {
  int lg = p >> 3, e = p & 7;
  return (e < 4) ? lg*4 + e : 16 + lg*4 + (e & 3);
}

// ---- GEMM C[m,n] = sum_k A[m,k]*Bt[n,k]  (K=512), fp32 in, cvt in staging ----
// MODE 0: z @ Wqk^T, epilogue = per-64-chunk l2-normalize -> g_qb (x 1/2pi) / g_kb
// MODE 1: (g_fA+g_fB) @ Wout^T + omega + b_out -> Cout fp32
template<int MODE>
__global__ __launch_bounds__(256, 2)
void gemm_bt(float* __restrict__ Cout, const float* __restrict__ add1,
             const float* __restrict__ add2, const float* __restrict__ Afp,
             const float* __restrict__ Bfp) {
  constexpr int K = 512;
  constexpr int N = (MODE == 0) ? 1024 : 512;
  __shared__ u16 As[128*72];
  __shared__ u16 Bs[128*72];
  const int m0 = blockIdx.x*128, n0 = blockIdx.y*128;
  const int t = threadIdx.x;
  const int w = t>>6, l = t&63;
  const int wr = (w>>1)*64, wc = (w&1)*64;
  const int lg = l>>4, li = l&15;
  const int srow = t>>3, scol = (t&7)*8;

  f32x4 acc[4][4] = {};

  for (int k0 = 0; k0 < K; k0 += 64) {
#pragma unroll
    for (int p = 0; p < 4; ++p) {
      int r = srow + p*32;
      {
        f32x4 b0 = *(const f32x4*)&Bfp[(size_t)(n0+r)*K + k0 + scol];
        f32x4 b1 = *(const f32x4*)&Bfp[(size_t)(n0+r)*K + k0 + scol + 4];
        *(short8*)&Bs[r*72 + scol] = cvt8(b0, b1);
      }
      if (MODE == 0) {
        f32x4 a0 = *(const f32x4*)&Afp[(size_t)(m0+r)*K + k0 + scol];
        f32x4 a1 = *(const f32x4*)&Afp[(size_t)(m0+r)*K + k0 + scol + 4];
        *(short8*)&As[r*72 + scol] = cvt8(a0, a1);
      } else {
        size_t off = (size_t)(m0+r)*K + k0 + scol;
        f32x4 a0 = *(const f32x4*)&g_fA[off];
        f32x4 a1 = *(const f32x4*)&g_fA[off+4];
        f32x4 c0 = *(const f32x4*)&g_fB[off];
        f32x4 c1 = *(const f32x4*)&g_fB[off+4];
        a0 += c0; a1 += c1;
        *(short8*)&As[r*72 + scol] = cvt8(a0, a1);
      }
    }
    __syncthreads();
#pragma unroll
    for (int ks = 0; ks < 2; ++ks) {
      short8 af[4], bf[4];
#pragma unroll
      for (int i = 0; i < 4; ++i)
        af[i] = *(const short8*)&As[(wr + i*16 + li)*72 + ks*32 + lg*8];
#pragma unroll
      for (int j = 0; j < 4; ++j)
        bf[j] = *(const short8*)&Bs[(wc + j*16 + li)*72 + ks*32 + lg*8];
#pragma unroll
      for (int i = 0; i < 4; ++i)
#pragma unroll
        for (int j = 0; j < 4; ++j)
          acc[i][j] = __builtin_amdgcn_mfma_f32_16x16x32_bf16(af[i], bf[j], acc[i][j], 0, 0, 0);
    }
    __syncthreads();
  }

  if (MODE == 0) {
    // fused per-head l2 normalize: each wave's 64-col tile is exactly one chunk
    const bool isq = (n0 < 512);
    u16* dst = isq ? g_qb : g_kb;
    const float qs = isq ? INV2PI : 1.0f;
    const int nb = (isq ? n0 : n0 - 512) + wc;
#pragma unroll
    for (int i = 0; i < 4; ++i) {
#pragma unroll
      for (int r = 0; r < 4; ++r) {
        float s = 0.f;
#pragma unroll
        for (int j = 0; j < 4; ++j) s += acc[i][j][r]*acc[i][j][r];
#pragma unroll
        for (int off = 1; off < 16; off <<= 1) s += __shfl_xor(s, off);
        float sc = qs / fmaxf(sqrtf(s), 1e-12f);
        int row = m0 + wr + i*16 + lg*4 + r;
#pragma unroll
        for (int j = 0; j < 4; ++j)
          dst[(size_t)row*D_ + nb + j*16 + li] = f2bf(acc[i][j][r]*sc);
      }
    }
  } else {
#pragma unroll
    for (int i = 0; i < 4; ++i) {
#pragma unroll
      for (int j = 0; j < 4; ++j) {
        int col = n0 + wc + j*16 + li;
        float badd = add1[col] + add2[col];
#pragma unroll
        for (int r = 0; r < 4; ++r) {
          int row = m0 + wr + i*16 + lg*4 + r;
          Cout[(size_t)row*N + col] = acc[i][j][r] + badd;
        }
      }
    }
  }
}

// ---- transpose k to [bh][d][t'] with PV slot permutation baked in ----
__global__ void transpose_k_kernel() {
  __shared__ u16 tile[64*72];
  const int t0 = blockIdx.x*64, bh = blockIdx.y;
  const int b = bh>>3, h = bh&7;
  const int t = threadIdx.x;
  {
    int r = t>>2, cs = (t&3)*16;
    const u16* src = g_kb + (size_t)(b*T_ + t0 + r)*D_ + h*64 + cs;
    *(short8*)&tile[r*72 + cs]     = *(const short8*)(src);
    *(short8*)&tile[r*72 + cs + 8] = *(const short8*)(src + 8);
  }
  __syncthreads();
  {
    int d = t>>2, ts = (t&3)*16;
    short8 o0, o1;
#pragma unroll
    for (int j = 0; j < 8; ++j) {
      int p0 = ts + j, p1 = ts + 8 + j;
      int s0 = (p0 & ~31) | perm5(p0 & 31);
      int s1 = (p1 & ~31) | perm5(p1 & 31);
      o0[j] = (short)tile[s0*72 + d];
      o1[j] = (short)tile[s1*72 + d];
    }
    u16* dst = g_kTp + ((size_t)bh*64 + d)*T_ + t0 + ts;
    *(short8*)(dst)     = o0;
    *(short8*)(dst + 8) = o1;
  }
}

// ---- fused  force = sin(Q K^T) K  per (b,h) ----
// 256-q-row tile per block (4 waves x 64 q): K/KT staging and fragment reads
// amortized over 2x MFMAs vs 128-row tile (LDS pipe was the binding resource).
// Double-buffered LDS, one barrier per kt, T14 split (loads early, ds_write late).
__global__ __launch_bounds__(256, 2)
void kuramoto_attn_kernel() {
  __shared__ u16 Ks[2][128*72];
  __shared__ u16 KTs[2][64*136];
  const int wg  = blockIdx.x;
  const int wgp = (wg & 7)*64 + (wg >> 3);   // XCD swizzle: 4 bh per XCD
  const int bh = wgp >> 4, qt = (wgp & 15) >> 1, kh = wgp & 1;
  const int b = bh >> 3, h = bh & 7;
  const int t = threadIdx.x;
  const int w = t>>6, l = t&63;
  const int lg = l>>4, li = l&15;

  // loop-invariant Q fragments (32 VGPR): wave w owns q rows w*64..w*64+63
  short8 bq[2][4];
#pragma unroll
  for (int ks = 0; ks < 2; ++ks)
#pragma unroll
    for (int j = 0; j < 4; ++j)
      bq[ks][j] = *(const short8*)&g_qb[(size_t)(b*T_ + qt*256 + w*64 + j*16 + li)*D_
                                        + h*64 + ks*32 + lg*8];

  const int sr = t>>3, sc = (t&7)*8;        // Ks staging coords (128x64)
  const int sd = t>>4, sk = (t&15)*8;       // KTs staging coords (64x128)
  const u16* kbase = g_kb  + (size_t)b*T_*D_ + h*64;
  const u16* tbase = g_kTp + (size_t)bh*64*T_;
  const int kt0 = kh*8;

  f32x4 acc_o[4][4] = {};

  // prologue: stage kt0 into buffer 0
#pragma unroll
  for (int p = 0; p < 4; ++p) {
    *(short8*)&Ks[0][(sr + p*32)*72 + sc] =
      *(const short8*)&kbase[(size_t)(kt0*128 + sr + p*32)*D_ + sc];
    *(short8*)&KTs[0][(sd + p*16)*136 + sk] =
      *(const short8*)&tbase[(size_t)(sd + p*16)*T_ + kt0*128 + sk];
  }
  __syncthreads();

#pragma unroll 2
  for (int ii = 0; ii < 8; ++ii) {
    const int buf = ii & 1;
    // issue next-tile global loads early (hidden under compute)
    short8 rk[4], rt[4];
    if (ii < 7) {
      const int ktn = kt0 + ii + 1;
#pragma unroll
      for (int p = 0; p < 4; ++p) {
        rk[p] = *(const short8*)&kbase[(size_t)(ktn*128 + sr + p*32)*D_ + sc];
        rt[p] = *(const short8*)&tbase[(size_t)(sd + p*16)*T_ + ktn*128 + sk];
      }
    }

    // compute on buf
#pragma unroll
    for (int kkp = 0; kkp < 4; ++kkp) {
      f32x4 sacc[2][4] = {};
#pragma unroll
      for (int ks = 0; ks < 2; ++ks) {
        short8 af0 = *(const short8*)&Ks[buf][((2*kkp  )*16 + li)*72 + ks*32 + lg*8];
        short8 af1 = *(const short8*)&Ks[buf][((2*kkp+1)*16 + li)*72 + ks*32 + lg*8];
#pragma unroll
        for (int j = 0; j < 4; ++j) {
          sacc[0][j] = __builtin_amdgcn_mfma_f32_16x16x32_bf16(af0, bq[ks][j], sacc[0][j], 0,0,0);
          sacc[1][j] = __builtin_amdgcn_mfma_f32_16x16x32_bf16(af1, bq[ks][j], sacc[1][j], 0,0,0);
        }
      }
      // sin -> bf16 pack: apv slot s holds P[q][perm5-permuted k], matched by g_kTp
      short8 apv[4];
#pragma unroll
      for (int j = 0; j < 4; ++j) {
        union { unsigned int u[4]; short8 s; } cv;
        cv.u[0] = (unsigned)f2bf(sin2pi(sacc[0][j][0])) | ((unsigned)f2bf(sin2pi(sacc[0][j][1]))<<16);
        cv.u[1] = (unsigned)f2bf(sin2pi(sacc[0][j][2])) | ((unsigned)f2bf(sin2pi(sacc[0][j][3]))<<16);
        cv.u[2] = (unsigned)f2bf(sin2pi(sacc[1][j][0])) | ((unsigned)f2bf(sin2pi(sacc[1][j][1]))<<16);
        cv.u[3] = (unsigned)f2bf(sin2pi(sacc[1][j][2])) | ((unsigned)f2bf(sin2pi(sacc[1][j][3]))<<16);
        apv[j] = cv.s;
      }
#pragma unroll
      for (int di = 0; di < 4; ++di) {
        short8 bv = *(const short8*)&KTs[buf][(di*16 + li)*136 + kkp*32 + lg*8];
#pragma unroll
        for (int j = 0; j < 4; ++j)
          acc_o[j][di] = __builtin_amdgcn_mfma_f32_16x16x32_bf16(apv[j], bv, acc_o[j][di], 0,0,0);
      }
    }

    // late ds_write of the prefetched tile into the other buffer
    if (ii < 7) {
#pragma unroll
      for (int p = 0; p < 4; ++p) {
        *(short8*)&Ks[buf^1][(sr + p*32)*72 + sc] = rk[p];
        *(short8*)&KTs[buf^1][(sd + p*16)*136 + sk] = rt[p];
      }
    }
    __syncthreads();
  }

  float* F = kh ? g_fB : g_fA;
#pragma unroll
  for (int j = 0; j < 4; ++j)
#pragma unroll
    for (int di = 0; di < 4; ++di)
#pragma unroll
      for (int r = 0; r < 4; ++r) {
        int row = b*T_ + qt*256 + w*64 + j*16 + lg*4 + r;
        int col = h*64 + di*16 + li;
        F[(size_t)row*D_ + col] = acc_o[j][di][r];
      }
}

extern "C" void kernel_launch(void* const* d_in, const int* in_sizes, int n_in,
                              void* d_out, int out_size, void* d_ws, size_t ws_size,
                              hipStream_t stream) {
  // inputs: t(unused), z, omega, W_qk, W_out, b_out  (all fp32)
  const float* z     = (const float*)d_in[1];
  const float* omega = (const float*)d_in[2];
  const float* Wqk   = (const float*)d_in[3];
  const float* Wout  = (const float*)d_in[4];
  const float* bout  = (const float*)d_in[5];
  float* out = (float*)d_out;

  gemm_bt<0><<<dim3(M_/128, 1024/128), 256, 0, stream>>>(nullptr, nullptr, nullptr, z, Wqk);
  transpose_k_kernel<<<dim3(T_/64, B_*H_), 256, 0, stream>>>();
  kuramoto_attn_kernel<<<512, 256, 0, stream>>>();
  gemm_bt<1><<<dim3(M_/128, 512/128), 256, 0, stream>>>(out, omega, bout, nullptr, Wout);
}

// Round 7
// 155.311 us; speedup vs baseline: 1.1747x; 1.0306x over previous
//
#include <hip/hip_runtime.h>
#include <hip/hip_bf16.h>

typedef unsigned short u16;
typedef _Float16 f16;
typedef __attribute__((ext_vector_type(8))) _Float16 f16x8;
typedef __attribute__((ext_vector_type(2))) __fp16 h16x2;   // cvt_pkrtz return type
typedef __attribute__((ext_vector_type(8))) short short8;
typedef __attribute__((ext_vector_type(4))) float f32x4;

#define B_ 4
#define T_ 2048
#define D_ 512
#define H_ 8
#define M_ (B_*T_)          // 8192 rows
#define INV2PI 0.15915494309189535f

// ---- static device workspace ----
__device__ f16 g_qb[M_*D_];                // normalized q /2pi   8 MB
__device__ f16 g_kb[M_*D_];                // normalized k        8 MB
__device__ f16 g_kTp[(size_t)B_*H_*64*T_]; // k^T, slot-permuted  8 MB
__device__ f16 g_force[(size_t)M_*D_];     // attention output    8 MB

__device__ inline float sin2pi(float x) {
#if __has_builtin(__builtin_amdgcn_sinf)
  return __builtin_amdgcn_sinf(x);   // v_sin_f32: sin(2*pi*x)
#else
  return __sinf(x * 6.283185307179586f);
#endif
}

// 8x fp32 -> fp16x8 via packed RTZ converts (1 instr per pair)
__device__ inline f16x8 cvt8h(f32x4 a, f32x4 b) {
  union { h16x2 h[4]; f16x8 v; } u;
  u.h[0] = __builtin_amdgcn_cvt_pkrtz(a[0], a[1]);
  u.h[1] = __builtin_amdgcn_cvt_pkrtz(a[2], a[3]);
  u.h[2] = __builtin_amdgcn_cvt_pkrtz(b[0], b[1]);
  u.h[3] = __builtin_amdgcn_cvt_pkrtz(b[2], b[3]);
  return u.v;
}

// slot permutation for the PV A-operand register layout:
// position p (0..31) in permuted storage holds original k = perm5(p)
__device__ inline int perm5(int p) {
  int lg = p >> 3, e = p & 7;
  return (e < 4) ? lg*4 + e : 16 + lg*4 + (e & 3);
}

// ---- GEMM C[m,n] = sum_k A[m,k]*Bt[n,k]  (K=512), fp16 MFMA ----
// MODE 0: z @ Wqk^T, epilogue = per-64-chunk l2-normalize -> g_qb (x 1/2pi) / g_kb
// MODE 1: g_force @ Wout^T + omega + b_out -> Cout fp32
template<int MODE>
__global__ __launch_bounds__(256, 2)
void gemm_bt(float* __restrict__ Cout, const float* __restrict__ add1,
             const float* __restrict__ add2, const float* __restrict__ Afp,
             const float* __restrict__ Bfp) {
  constexpr int K = 512;
  constexpr int N = (MODE == 0) ? 1024 : 512;
  __shared__ f16 As[128*72];
  __shared__ f16 Bs[128*72];
  const int m0 = blockIdx.x*128, n0 = blockIdx.y*128;
  const int t = threadIdx.x;
  const int w = t>>6, l = t&63;
  const int wr = (w>>1)*64, wc = (w&1)*64;
  const int lg = l>>4, li = l&15;
  const int srow = t>>3, scol = (t&7)*8;

  f32x4 acc[4][4] = {};

  for (int k0 = 0; k0 < K; k0 += 64) {
#pragma unroll
    for (int p = 0; p < 4; ++p) {
      int r = srow + p*32;
      {
        f32x4 b0 = *(const f32x4*)&Bfp[(size_t)(n0+r)*K + k0 + scol];
        f32x4 b1 = *(const f32x4*)&Bfp[(size_t)(n0+r)*K + k0 + scol + 4];
        *(f16x8*)&Bs[r*72 + scol] = cvt8h(b0, b1);
      }
      if (MODE == 0) {
        f32x4 a0 = *(const f32x4*)&Afp[(size_t)(m0+r)*K + k0 + scol];
        f32x4 a1 = *(const f32x4*)&Afp[(size_t)(m0+r)*K + k0 + scol + 4];
        *(f16x8*)&As[r*72 + scol] = cvt8h(a0, a1);
      } else {
        *(short8*)&As[r*72 + scol] =
          *(const short8*)&g_force[(size_t)(m0+r)*K + k0 + scol];
      }
    }
    __syncthreads();
#pragma unroll
    for (int ks = 0; ks < 2; ++ks) {
      f16x8 af[4], bf[4];
#pragma unroll
      for (int i = 0; i < 4; ++i)
        af[i] = *(const f16x8*)&As[(wr + i*16 + li)*72 + ks*32 + lg*8];
#pragma unroll
      for (int j = 0; j < 4; ++j)
        bf[j] = *(const f16x8*)&Bs[(wc + j*16 + li)*72 + ks*32 + lg*8];
#pragma unroll
      for (int i = 0; i < 4; ++i)
#pragma unroll
        for (int j = 0; j < 4; ++j)
          acc[i][j] = __builtin_amdgcn_mfma_f32_16x16x32_f16(af[i], bf[j], acc[i][j], 0, 0, 0);
    }
    __syncthreads();
  }

  if (MODE == 0) {
    // fused per-head l2 normalize: each wave's 64-col tile is exactly one chunk
    const bool isq = (n0 < 512);
    f16* dst = isq ? g_qb : g_kb;
    const float qs = isq ? INV2PI : 1.0f;
    const int nb = (isq ? n0 : n0 - 512) + wc;
#pragma unroll
    for (int i = 0; i < 4; ++i) {
#pragma unroll
      for (int r = 0; r < 4; ++r) {
        float s = 0.f;
#pragma unroll
        for (int j = 0; j < 4; ++j) s += acc[i][j][r]*acc[i][j][r];
#pragma unroll
        for (int off = 1; off < 16; off <<= 1) s += __shfl_xor(s, off);
        float sc = qs / fmaxf(sqrtf(s), 1e-12f);
        int row = m0 + wr + i*16 + lg*4 + r;
#pragma unroll
        for (int j = 0; j < 4; ++j)
          dst[(size_t)row*D_ + nb + j*16 + li] = (f16)(acc[i][j][r]*sc);
      }
    }
  } else {
#pragma unroll
    for (int i = 0; i < 4; ++i) {
#pragma unroll
      for (int j = 0; j < 4; ++j) {
        int col = n0 + wc + j*16 + li;
        float badd = add1[col] + add2[col];
#pragma unroll
        for (int r = 0; r < 4; ++r) {
          int row = m0 + wr + i*16 + lg*4 + r;
          Cout[(size_t)row*N + col] = acc[i][j][r] + badd;
        }
      }
    }
  }
}

// ---- transpose k to [bh][d][t'] with PV slot permutation baked in ----
__global__ void transpose_k_kernel() {
  __shared__ u16 tile[64*72];
  const int t0 = blockIdx.x*64, bh = blockIdx.y;
  const int b = bh>>3, h = bh&7;
  const int t = threadIdx.x;
  const u16* kb = (const u16*)g_kb;
  u16* kT = (u16*)g_kTp;
  {
    int r = t>>2, cs = (t&3)*16;
    const u16* src = kb + (size_t)(b*T_ + t0 + r)*D_ + h*64 + cs;
    *(short8*)&tile[r*72 + cs]     = *(const short8*)(src);
    *(short8*)&tile[r*72 + cs + 8] = *(const short8*)(src + 8);
  }
  __syncthreads();
  {
    int d = t>>2, ts = (t&3)*16;
    short8 o0, o1;
#pragma unroll
    for (int j = 0; j < 8; ++j) {
      int p0 = ts + j, p1 = ts + 8 + j;
      int s0 = (p0 & ~31) | perm5(p0 & 31);
      int s1 = (p1 & ~31) | perm5(p1 & 31);
      o0[j] = (short)tile[s0*72 + d];
      o1[j] = (short)tile[s1*72 + d];
    }
    u16* dst = kT + ((size_t)bh*64 + d)*T_ + t0 + ts;
    *(short8*)(dst)     = o0;
    *(short8*)(dst + 8) = o1;
  }
}

// ---- fused  force = sin(Q K^T) K  per (b,h) ----
// 256-q-row tile, full kt range (no split), grid 256 = 1 block/CU.
// T15 2-deep pipeline: QK MFMAs of kkp+1 issue BEFORE sin/PV of kkp, so the
// wave feeds the matrix pipe and then immediately issues sin VALU -> overlap.
// fp16 + cvt_pkrtz kills the bf16-RNE conversion cost (~half of old VALU).
__global__ __launch_bounds__(256)
void kuramoto_attn_kernel() {
  __shared__ u16 Ks[2][128*72];
  __shared__ u16 KTs[2][64*136];
  const int wg  = blockIdx.x;
  const int wgp = (wg & 7)*32 + (wg >> 3);   // XCD swizzle: 4 bh per XCD
  const int bh = wgp >> 3, qt = wgp & 7;
  const int b = bh >> 3, h = bh & 7;
  const int t = threadIdx.x;
  const int w = t>>6, l = t&63;
  const int lg = l>>4, li = l&15;

  // loop-invariant Q fragments (32 VGPR): wave w owns q rows w*64..w*64+63
  f16x8 bq[2][4];
#pragma unroll
  for (int ks = 0; ks < 2; ++ks)
#pragma unroll
    for (int j = 0; j < 4; ++j)
      bq[ks][j] = *(const f16x8*)&g_qb[(size_t)(b*T_ + qt*256 + w*64 + j*16 + li)*D_
                                       + h*64 + ks*32 + lg*8];

  const int sr = t>>3, sc = (t&7)*8;        // Ks staging coords (128x64)
  const int sd = t>>4, sk = (t&15)*8;       // KTs staging coords (64x128)
  const u16* kbase = (const u16*)g_kb  + (size_t)b*T_*D_ + h*64;
  const u16* tbase = (const u16*)g_kTp + (size_t)bh*64*T_;

  f32x4 acc_o[4][4] = {};

  // prologue: stage kt 0 into buffer 0
#pragma unroll
  for (int p = 0; p < 4; ++p) {
    *(short8*)&Ks[0][(sr + p*32)*72 + sc] =
      *(const short8*)&kbase[(size_t)(sr + p*32)*D_ + sc];
    *(short8*)&KTs[0][(sd + p*16)*136 + sk] =
      *(const short8*)&tbase[(size_t)(sd + p*16)*T_ + sk];
  }
  __syncthreads();

#define QK_STEP(KKP, S) do {                                                   \
  _Pragma("unroll") for (int ks = 0; ks < 2; ++ks) {                           \
    f16x8 af0 = *(const f16x8*)&Ks[buf][((2*(KKP)  )*16 + li)*72 + ks*32 + lg*8]; \
    f16x8 af1 = *(const f16x8*)&Ks[buf][((2*(KKP)+1)*16 + li)*72 + ks*32 + lg*8]; \
    _Pragma("unroll") for (int j = 0; j < 4; ++j) {                            \
      S[0][j] = __builtin_amdgcn_mfma_f32_16x16x32_f16(af0, bq[ks][j], S[0][j], 0,0,0); \
      S[1][j] = __builtin_amdgcn_mfma_f32_16x16x32_f16(af1, bq[ks][j], S[1][j], 0,0,0); \
    } } } while(0)

#define SINPV_STEP(KKP, S) do {                                                \
  f16x8 apv[4];                                                                \
  _Pragma("unroll") for (int j = 0; j < 4; ++j) {                              \
    union { h16x2 h[4]; f16x8 v; } cv;                                         \
    cv.h[0] = __builtin_amdgcn_cvt_pkrtz(sin2pi(S[0][j][0]), sin2pi(S[0][j][1])); \
    cv.h[1] = __builtin_amdgcn_cvt_pkrtz(sin2pi(S[0][j][2]), sin2pi(S[0][j][3])); \
    cv.h[2] = __builtin_amdgcn_cvt_pkrtz(sin2pi(S[1][j][0]), sin2pi(S[1][j][1])); \
    cv.h[3] = __builtin_amdgcn_cvt_pkrtz(sin2pi(S[1][j][2]), sin2pi(S[1][j][3])); \
    apv[j] = cv.v; }                                                           \
  _Pragma("unroll") for (int di = 0; di < 4; ++di) {                           \
    f16x8 bv = *(const f16x8*)&KTs[buf][(di*16 + li)*136 + (KKP)*32 + lg*8];   \
    _Pragma("unroll") for (int j = 0; j < 4; ++j)                              \
      acc_o[j][di] = __builtin_amdgcn_mfma_f32_16x16x32_f16(apv[j], bv, acc_o[j][di], 0,0,0); \
  } } while(0)

#pragma unroll 2
  for (int ii = 0; ii < 16; ++ii) {
    const int buf = ii & 1;
    // issue next-tile global loads early (hidden under compute)
    short8 rk[4], rt[4];
    if (ii < 15) {
      const int ktn = ii + 1;
#pragma unroll
      for (int p = 0; p < 4; ++p) {
        rk[p] = *(const short8*)&kbase[(size_t)(ktn*128 + sr + p*32)*D_ + sc];
        rt[p] = *(const short8*)&tbase[(size_t)(sd + p*16)*T_ + ktn*128 + sk];
      }
    }

    // 2-deep pipelined compute: QK[kkp+1] in flight while sin/PV[kkp] runs
    f32x4 sA[2][4] = {};
    f32x4 sB[2][4] = {};
    QK_STEP(0, sA);
    QK_STEP(1, sB);  SINPV_STEP(0, sA);
#pragma unroll
    for (int z = 0; z < 2; ++z)
#pragma unroll
      for (int j = 0; j < 4; ++j) sA[z][j] = (f32x4)(0.f);
    QK_STEP(2, sA);  SINPV_STEP(1, sB);
#pragma unroll
    for (int z = 0; z < 2; ++z)
#pragma unroll
      for (int j = 0; j < 4; ++j) sB[z][j] = (f32x4)(0.f);
    QK_STEP(3, sB);  SINPV_STEP(2, sA);
                     SINPV_STEP(3, sB);

    // late ds_write of the prefetched tile into the other buffer
    if (ii < 15) {
#pragma unroll
      for (int p = 0; p < 4; ++p) {
        *(short8*)&Ks[buf^1][(sr + p*32)*72 + sc] = rk[p];
        *(short8*)&KTs[buf^1][(sd + p*16)*136 + sk] = rt[p];
      }
    }
    __syncthreads();
  }
#undef QK_STEP
#undef SINPV_STEP

  // write force fp16 (row-major [b*T+t][h*64+d])
#pragma unroll
  for (int j = 0; j < 4; ++j)
#pragma unroll
    for (int di = 0; di < 4; ++di)
#pragma unroll
      for (int r = 0; r < 4; ++r) {
        int row = b*T_ + qt*256 + w*64 + j*16 + lg*4 + r;
        int col = h*64 + di*16 + li;
        g_force[(size_t)row*D_ + col] = (f16)acc_o[j][di][r];
      }
}

extern "C" void kernel_launch(void* const* d_in, const int* in_sizes, int n_in,
                              void* d_out, int out_size, void* d_ws, size_t ws_size,
                              hipStream_t stream) {
  // inputs: t(unused), z, omega, W_qk, W_out, b_out  (all fp32)
  const float* z     = (const float*)d_in[1];
  const float* omega = (const float*)d_in[2];
  const float* Wqk   = (const float*)d_in[3];
  const float* Wout  = (const float*)d_in[4];
  const float* bout  = (const float*)d_in[5];
  float* out = (float*)d_out;

  gemm_bt<0><<<dim3(M_/128, 1024/128), 256, 0, stream>>>(nullptr, nullptr, nullptr, z, Wqk);
  transpose_k_kernel<<<dim3(T_/64, B_*H_), 256, 0, stream>>>();
  kuramoto_attn_kernel<<<256, 256, 0, stream>>>();
  gemm_bt<1><<<dim3(M_/128, 512/128), 256, 0, stream>>>(out, omega, bout, nullptr, Wout);
}